// Round 1
// baseline (1658.643 us; speedup 1.0000x reference)
//
#include <hip/hip_runtime.h>
#include <stdint.h>

// SuperRGCNLayer on MI355X.
// Design: counting-sort edges by relation (16 buckets), then per-relation
// gather-GEMM-scatter: 64-edge tiles, W[rel] + gathered X rows in LDS,
// fp32 4x4 micro-tile per thread, HW fp32 atomics into bias-initialized out.
// Workspace need: 262912 + 10*E bytes (~16.3 MB).

#define TPB 256

// ---------------- W construction -------------------------------------------
// Reference does:  w_flat = weight.reshape(64,8,64)   (raw reinterpret)
//                  comb   = w_comp(16,8) @ w_flat -> (64,16,64)
//                  W      = comb.reshape(16,64,64)    (raw reinterpret)
// which collapses to: W[m][o][i] = sum_b w_comp[o%16][b] * weight[(m*4+o/16)*512 + b*64 + i]
// We store transposed Wt[m][i][o] (B-operand layout for the GEMM).
__global__ void k_build_w(const float* __restrict__ weight,
                          const float* __restrict__ w_comp,
                          float* __restrict__ Wt, int* __restrict__ cnt) {
  const int tid = threadIdx.x;
  if (tid < 16) cnt[tid] = 0;  // zero rel histogram for this call
  for (int idx = tid; idx < 16 * 64 * 64; idx += TPB) {
    const int m = idx >> 12;
    const int i = (idx >> 6) & 63;
    const int o = idx & 63;
    const float* wc = w_comp + ((o & 15) << 3);
    const float* wf = weight + (((m << 2) + (o >> 4)) << 9) + i;
    float s = 0.f;
#pragma unroll
    for (int b = 0; b < 8; ++b) s = fmaf(wc[b], wf[b << 6], s);
    Wt[idx] = s;  // Wt[m][i][o]
  }
}

// ---------------- histogram by relation ------------------------------------
__global__ void k_hist(const int* __restrict__ nt, const int* __restrict__ esrc,
                       const int* __restrict__ edst, const int* __restrict__ etyp,
                       unsigned char* __restrict__ relRaw, int* __restrict__ cnt,
                       int E) {
  __shared__ int lc[16];
  const int tid = threadIdx.x;
  if (tid < 16) lc[tid] = 0;
  __syncthreads();
  const int e = blockIdx.x * TPB + tid;
  if (e < E) {
    const int r = nt[esrc[e]] * 8 + nt[edst[e]] * 4 + etyp[e];
    relRaw[e] = (unsigned char)r;
    atomicAdd(&lc[r], 1);
  }
  __syncthreads();
  if (tid < 16 && lc[tid]) atomicAdd(&cnt[tid], lc[tid]);
}

// ---------------- 16-bin exclusive scan ------------------------------------
__global__ void k_scan(const int* __restrict__ cnt, int* __restrict__ offs,
                       int* __restrict__ cursor) {
  if (threadIdx.x == 0) {
    int run = 0;
    for (int r = 0; r < 16; ++r) { offs[r] = run; cursor[r] = run; run += cnt[r]; }
    offs[16] = run;  // == E
  }
}

// ---------------- bucket scatter (block-aggregated) -------------------------
__global__ void k_scatter(const int* __restrict__ esrc, const int* __restrict__ edst,
                          const unsigned char* __restrict__ relRaw,
                          int* __restrict__ cursor, int* __restrict__ srcS,
                          int* __restrict__ dstS, unsigned char* __restrict__ relS,
                          int E) {
  __shared__ int lc[16], lb[16];
  const int tid = threadIdx.x;
  if (tid < 16) lc[tid] = 0;
  __syncthreads();
  const int e = blockIdx.x * TPB + tid;
  int r = 0, lpos = 0;
  const bool ok = (e < E);
  if (ok) {
    r = relRaw[e];
    lpos = atomicAdd(&lc[r], 1);
  }
  __syncthreads();
  if (tid < 16 && lc[tid]) lb[tid] = atomicAdd(&cursor[tid], lc[tid]);
  __syncthreads();
  if (ok) {
    const int pos = lb[r] + lpos;
    srcS[pos] = esrc[e];
    dstS[pos] = edst[e];
    relS[pos] = (unsigned char)r;
  }
}

// ---------------- out = bias ------------------------------------------------
__global__ void k_init(float* __restrict__ out, const float* __restrict__ bias,
                       int total) {
  const int i = blockIdx.x * blockDim.x + threadIdx.x;
  if (i < total) out[i] = bias[i & 63];
}

// ---------------- main: per-rel gather-GEMM-scatter -------------------------
// Tile = 64 consecutive edges of the rel-sorted array; a tile crossing a
// bucket boundary is processed as (rare) sub-segments, one rel each.
__global__ __launch_bounds__(TPB) void k_gemm(
    const float* __restrict__ x, const float* __restrict__ Wt,
    const int* __restrict__ offs_g, const int* __restrict__ srcS,
    const int* __restrict__ dstS, const unsigned char* __restrict__ relS,
    float* __restrict__ out, int E) {
  __shared__ float Wl[4096];      // Wt[r]: [i][o], 16 KB
  __shared__ float Xl[64 * 68];   // gathered rows, stride 68 (bank-spread, 16B-aligned)
  __shared__ int dstl[64];
  __shared__ int offs[17];
  const int tid = threadIdx.x;
  if (tid < 17) offs[tid] = offs_g[tid];
  __syncthreads();

  const int jb = blockIdx.x << 6;
  const int je = min(jb + 64, E);
  const int e = tid >> 2, q = tid & 3;       // gather role: 4 threads per row
  const int co = tid & 15, re = tid >> 4;    // compute role: 16x16 thread grid

  int j0 = jb;
  while (j0 < je) {
    const int r = relS[j0];                  // uniform across block
    const int j1 = min(je, offs[r + 1]);
    const int n = j1 - j0;

    // stage W[r] (16 KB, coalesced float4)
    {
      const float4* Wg4 = (const float4*)(Wt + (r << 12));
      float4* Wl4 = (float4*)Wl;
#pragma unroll
      for (int u = 0; u < 4; ++u) Wl4[tid + (u << 8)] = Wg4[tid + (u << 8)];
    }
    // gather X rows (zero-fill beyond segment) + dst list
    {
      float4 z = {0.f, 0.f, 0.f, 0.f};
      float4 v0 = z, v1 = z, v2 = z, v3 = z;
      if (e < n) {
        const float4* xr = (const float4*)(x + ((size_t)srcS[j0 + e] << 6)) + (q << 2);
        v0 = xr[0]; v1 = xr[1]; v2 = xr[2]; v3 = xr[3];
      }
      float* xd = &Xl[e * 68 + (q << 4)];
      *(float4*)(xd)      = v0;
      *(float4*)(xd + 4)  = v1;
      *(float4*)(xd + 8)  = v2;
      *(float4*)(xd + 12) = v3;
      if (q == 0) dstl[e] = (e < n) ? dstS[j0 + e] : -1;
    }
    __syncthreads();

    // 64x64 = X(64e x 64i) @ Wt(64i x 64o); thread (re,co) owns rows re*4+j, cols co*4+l
    float acc[4][4] = {};
    const float* xbase = &Xl[(re << 2) * 68];
#pragma unroll 4
    for (int k4 = 0; k4 < 64; k4 += 4) {
      const float4 xv0 = *(const float4*)(xbase + k4);
      const float4 xv1 = *(const float4*)(xbase + 68 + k4);
      const float4 xv2 = *(const float4*)(xbase + 136 + k4);
      const float4 xv3 = *(const float4*)(xbase + 204 + k4);
#pragma unroll
      for (int kk = 0; kk < 4; ++kk) {
        const float4 wv = *(const float4*)&Wl[((k4 + kk) << 6) + (co << 2)];
        const float a0 = ((const float*)&xv0)[kk];
        const float a1 = ((const float*)&xv1)[kk];
        const float a2 = ((const float*)&xv2)[kk];
        const float a3 = ((const float*)&xv3)[kk];
        acc[0][0] = fmaf(a0, wv.x, acc[0][0]); acc[0][1] = fmaf(a0, wv.y, acc[0][1]);
        acc[0][2] = fmaf(a0, wv.z, acc[0][2]); acc[0][3] = fmaf(a0, wv.w, acc[0][3]);
        acc[1][0] = fmaf(a1, wv.x, acc[1][0]); acc[1][1] = fmaf(a1, wv.y, acc[1][1]);
        acc[1][2] = fmaf(a1, wv.z, acc[1][2]); acc[1][3] = fmaf(a1, wv.w, acc[1][3]);
        acc[2][0] = fmaf(a2, wv.x, acc[2][0]); acc[2][1] = fmaf(a2, wv.y, acc[2][1]);
        acc[2][2] = fmaf(a2, wv.z, acc[2][2]); acc[2][3] = fmaf(a2, wv.w, acc[2][3]);
        acc[3][0] = fmaf(a3, wv.x, acc[3][0]); acc[3][1] = fmaf(a3, wv.y, acc[3][1]);
        acc[3][2] = fmaf(a3, wv.z, acc[3][2]); acc[3][3] = fmaf(a3, wv.w, acc[3][3]);
      }
    }

    // scatter-add (HW fp32 atomics; out rows are L3-resident)
#pragma unroll
    for (int j = 0; j < 4; ++j) {
      const int d = dstl[(re << 2) + j];
      if (d >= 0) {
        float* op = out + ((size_t)d << 6) + (co << 2);
        unsafeAtomicAdd(op + 0, acc[j][0]);
        unsafeAtomicAdd(op + 1, acc[j][1]);
        unsafeAtomicAdd(op + 2, acc[j][2]);
        unsafeAtomicAdd(op + 3, acc[j][3]);
      }
    }
    __syncthreads();
    j0 = j1;
  }
}

// ---------------- launch ----------------------------------------------------
extern "C" void kernel_launch(void* const* d_in, const int* in_sizes, int n_in,
                              void* d_out, int out_size, void* d_ws, size_t ws_size,
                              hipStream_t stream) {
  const float* x      = (const float*)d_in[0];
  const int* nt       = (const int*)d_in[1];
  const int* esrc     = (const int*)d_in[2];
  const int* edst     = (const int*)d_in[3];
  const int* etyp     = (const int*)d_in[4];
  const float* weight = (const float*)d_in[5];
  const float* w_comp = (const float*)d_in[6];
  const float* bias   = (const float*)d_in[7];
  float* out = (float*)d_out;
  const int N = in_sizes[1];
  const int E = in_sizes[2];

  char* w = (char*)d_ws;
  float* Wt            = (float*)w;                                  // 262144 B
  int* cnt             = (int*)(w + 262144);                         // 64 B
  int* offs            = (int*)(w + 262144 + 256);                   // 68 B
  int* cursor          = (int*)(w + 262144 + 512);                   // 64 B
  int* srcS            = (int*)(w + 262912);                         // 4E
  int* dstS            = (int*)(w + 262912 + (size_t)E * 4);         // 4E
  unsigned char* relRaw = (unsigned char*)(w + 262912 + (size_t)E * 8);  // E
  unsigned char* relS   = relRaw + E;                                // E
  const size_t need = 262912 + (size_t)E * 10;
  if (ws_size < need) return;  // cannot run without scratch

  const int ebl = (E + TPB - 1) / TPB;
  const int tot = N * 64;

  hipLaunchKernelGGL(k_build_w, dim3(1), dim3(TPB), 0, stream, weight, w_comp, Wt, cnt);
  hipLaunchKernelGGL(k_hist, dim3(ebl), dim3(TPB), 0, stream, nt, esrc, edst, etyp, relRaw, cnt, E);
  hipLaunchKernelGGL(k_scan, dim3(1), dim3(64), 0, stream, cnt, offs, cursor);
  hipLaunchKernelGGL(k_scatter, dim3(ebl), dim3(TPB), 0, stream, esrc, edst, relRaw, cursor, srcS, dstS, relS, E);
  hipLaunchKernelGGL(k_init, dim3((tot + 1023) / 1024), dim3(1024), 0, stream, out, bias, tot);
  hipLaunchKernelGGL(k_gemm, dim3((E + 63) / 64), dim3(TPB), 0, stream, x, Wt, offs, srcS, dstS, relS, out, E);
}